// Round 1
// baseline (889.977 us; speedup 1.0000x reference)
//
#include <hip/hip_runtime.h>
#include <hip/hip_bf16.h>
#include <stdint.h>

// Problem constants: E,B,S,D,F = 8,8,2048,1024,4096. Inputs/outputs are f32.
#define E_ 8
#define B_ 8
#define S_ 2048
#define D_ 1024
#define F_ 4096

typedef short short8 __attribute__((ext_vector_type(8)));   // 8 bf16 = 4 VGPRs
typedef float f32x4  __attribute__((ext_vector_type(4)));
typedef unsigned short u16;

union U16x8 { uint4 v; u16 s[8]; };
union U16x4 { uint2 v; u16 s[4]; };

__device__ __forceinline__ float gelu_exact(float x) {
    return 0.5f * x * (1.0f + erff(x * 0.70710678118654752f));
}
__device__ __forceinline__ u16 f2b(float v) {
    __hip_bfloat16 b = __float2bfloat16(v);
    return *(const u16*)&b;
}

// Async global->LDS, 16 B per lane. LDS dest = wave-uniform base + lane*16.
__device__ __forceinline__ void gload_lds16(const u16* g, u16* l) {
    __builtin_amdgcn_global_load_lds(
        (const __attribute__((address_space(1))) uint32_t*)g,
        (__attribute__((address_space(3))) uint32_t*)l, 16, 0, 0);
}

// Sync / wait primitives (raw: no vmcnt drain at barriers)
#define SBAR asm volatile("s_barrier" ::: "memory")
#define WLG0 asm volatile("s_waitcnt lgkmcnt(0)" ::: "memory")
#define WVM8 asm volatile("s_waitcnt vmcnt(8)" ::: "memory")
#define WVM4 asm volatile("s_waitcnt vmcnt(4)" ::: "memory")
#define WVM0 asm volatile("s_waitcnt vmcnt(0)" ::: "memory")

// ===========================================================================
// Prep kernels (one-time, memory-bound)
// ===========================================================================
__global__ void convert_x(const float* __restrict__ X, u16* __restrict__ Xb) {
    const size_t i = ((size_t)blockIdx.x * 256 + threadIdx.x) * 8;
    const float4 v0 = *(const float4*)(X + i);
    const float4 v1 = *(const float4*)(X + i + 4);
    U16x8 o;
    o.s[0] = f2b(v0.x); o.s[1] = f2b(v0.y); o.s[2] = f2b(v0.z); o.s[3] = f2b(v0.w);
    o.s[4] = f2b(v1.x); o.s[5] = f2b(v1.y); o.s[6] = f2b(v1.z); o.s[7] = f2b(v1.w);
    *(uint4*)(Xb + i) = o.v;
}

// src f32 [z][R][C] -> dst bf16 [z][C][R]  (64x64 tiles)
__global__ void transpose_w(const float* __restrict__ src, u16* __restrict__ dst,
                            int R, int C) {
    __shared__ u16 tile[64 * 72];
    const int c0 = blockIdx.x * 64;
    const int r0 = blockIdx.y * 64;
    const size_t base = (size_t)blockIdx.z * R * C;
    const int t  = threadIdx.x;
    const int rr = t >> 4;            // 0..15
    const int cc = (t & 15) * 4;      // 0..60
#pragma unroll
    for (int p = 0; p < 4; ++p) {
        const int r = rr + p * 16;
        const float4 v = *(const float4*)(src + base + (size_t)(r0 + r) * C + c0 + cc);
        tile[(cc + 0) * 72 + r] = f2b(v.x);
        tile[(cc + 1) * 72 + r] = f2b(v.y);
        tile[(cc + 2) * 72 + r] = f2b(v.z);
        tile[(cc + 3) * 72 + r] = f2b(v.w);
    }
    __syncthreads();
    const int cn = t >> 2;            // 0..63 (dst row within tile)
    const int ch = (t & 3) * 4;       // 0..12
#pragma unroll
    for (int p = 0; p < 4; ++p) {
        const int rch = ch + p * 16;  // 0..60
        *(uint2*)(dst + base + (size_t)(c0 + cn) * R + r0 + rch) =
            *(const uint2*)(tile + cn * 72 + rch);
    }
}

// ===========================================================================
// 8-phase 256-wide GEMM kernels (T3+T4 counted vmcnt, T5 setprio).
//
// LDS (128 KiB as u16[65536]): 2 buffers x 4 regions x 8192 u16 (16 KB):
//   buf*32768 + { A_k0:0, A_k1:8192, B_k0:16384, B_k1:24576 }
// Region = 256 rows x 32 k-elems, row = 64 B (4 granules of 16 B).
// ds_read_b128 frag reads land 8 lanes per 4-bank quad = conflict floor,
// so LINEAR LDS (no swizzle) and contiguous global_load_lds destinations.
//
// Per-iteration schedule (tiles T0=2u in buf0 at p0-3, T1=2u+1 in buf1 at
// p4-7; each region restaged one barrier after its last read; vmcnt(8) = 4
// regions in flight, at end of odd phases only):
//   p0: rd buf0.k0 (qi=0,+B)  stage buf1.A_k1 <- T1
//   p1: rd buf0.k0 (qi=1)     stage buf1.B_k1 <- T1      vm8
//   p2: rd buf0.k1 (qi=0,+B)  stage buf0.A_k0 <- T0+2
//   p3: rd buf0.k1 (qi=1)     stage buf0.B_k0 <- T0+2    vm8
//   p4: rd buf1.k0 (qi=0,+B)  stage buf0.A_k1 <- T0+2
//   p5: rd buf1.k0 (qi=1)     stage buf0.B_k1 <- T0+2    vm8
//   p6: rd buf1.k1 (qi=0,+B)  stage buf1.A_k0 <- T1+2
//   p7: rd buf1.k1 (qi=1)     stage buf1.B_k0 <- T1+2    vm8
// Epilogue iteration stages only buf1.k1 <- NT-1; waits vm8 / vm4 / vm0.
// ===========================================================================

// ---------------- gateup: H = gelu(Xb@W1t^T) * (Xb@W3t^T) ------------------
// Tile 256(s) x 128(f); wave grid 4x2 (wr=w>>1, wc=w&1); per-wave 64x64,
// two accumulators (gate/up). B region = B1(128x32) + B3(128x32).
__global__ __launch_bounds__(512, 2)
void gateup_v3(const u16* __restrict__ Xb, const u16* __restrict__ W1t,
               const u16* __restrict__ W3t, const int* __restrict__ langs,
               u16* __restrict__ H)
{
    __shared__ u16 lds[65536];
    const int f0 = blockIdx.x * 128;
    const int s0 = blockIdx.y * 256;
    const int b  = blockIdx.z;
    const int e  = (langs[b] - 4) & 7;

    const int t    = threadIdx.x;
    const int lane = t & 63;
    const int w    = t >> 6;          // 0..7
    const int wr   = w >> 1, wc = w & 1;
    const int lm   = lane & 15, lq = lane >> 4;
    const int sr   = lane >> 2, sg = lane & 3;   // staging: row-in-16 / granule

    // staging source pointers (per-lane global addr; LDS dest stays linear)
    const u16* xg   = Xb + ((size_t)b * S_ + s0 + w * 32 + sr) * D_ + sg * 8;
    const u16* bsrc = (w < 4 ? W1t : W3t)
                    + ((size_t)e * F_ + f0 + (w & 3) * 32 + sr) * D_ + sg * 8;
    const int aofs = w * 1024;                                  // within A region
    const int bofs = 16384 + (w >> 2) * 4096 + (w & 3) * 1024;  // within buf

    f32x4 acc1[4][4], acc2[4][4];
#pragma unroll
    for (int i = 0; i < 4; ++i)
#pragma unroll
        for (int j = 0; j < 4; ++j) {
            acc1[i][j] = (f32x4){0.f, 0.f, 0.f, 0.f};
            acc2[i][j] = (f32x4){0.f, 0.f, 0.f, 0.f};
        }
    short8 a[2], b1[4], b3[4];

#define GU_STA(bf, kh, kt) do { \
    gload_lds16(xg + (size_t)(kt) * 64 + (kh) * 32, \
                lds + (bf) * 32768 + (kh) * 8192 + aofs); \
    gload_lds16(xg + (size_t)16 * D_ + (size_t)(kt) * 64 + (kh) * 32, \
                lds + (bf) * 32768 + (kh) * 8192 + aofs + 512); } while (0)
#define GU_STB(bf, kh, kt) do { \
    gload_lds16(bsrc + (size_t)(kt) * 64 + (kh) * 32, \
                lds + (bf) * 32768 + (kh) * 8192 + bofs); \
    gload_lds16(bsrc + (size_t)16 * D_ + (size_t)(kt) * 64 + (kh) * 32, \
                lds + (bf) * 32768 + (kh) * 8192 + bofs + 512); } while (0)
#define GU_RD(bf, kh, qi, LOADB) do { \
    const u16* ab_ = lds + (bf) * 32768 + (kh) * 8192; \
    _Pragma("unroll") \
    for (int i2 = 0; i2 < 2; ++i2) \
        a[i2] = *(const short8*)(ab_ + (wr * 64 + (qi) * 32 + i2 * 16 + lm) * 32 + lq * 8); \
    if (LOADB) { \
        const u16* bb_ = ab_ + 16384; \
        _Pragma("unroll") \
        for (int j = 0; j < 4; ++j) { \
            b1[j] = *(const short8*)(bb_ + (wc * 64 + j * 16 + lm) * 32 + lq * 8); \
            b3[j] = *(const short8*)(bb_ + 4096 + (wc * 64 + j * 16 + lm) * 32 + lq * 8); \
        } } } while (0)
#define GU_MM(qi) do { \
    __builtin_amdgcn_s_setprio(1); \
    _Pragma("unroll") \
    for (int i2 = 0; i2 < 2; ++i2) \
    _Pragma("unroll") \
    for (int j = 0; j < 4; ++j) { \
        acc1[(qi)*2 + i2][j] = __builtin_amdgcn_mfma_f32_16x16x32_bf16(a[i2], b1[j], acc1[(qi)*2 + i2][j], 0, 0, 0); \
        acc2[(qi)*2 + i2][j] = __builtin_amdgcn_mfma_f32_16x16x32_bf16(a[i2], b3[j], acc2[(qi)*2 + i2][j], 0, 0, 0); \
    } \
    __builtin_amdgcn_s_setprio(0); } while (0)
#define GU_PH(bf, kh, qi, LOADB, STG, WT) do { \
    GU_RD(bf, kh, qi, LOADB); STG; SBAR; GU_MM(qi); WT; WLG0; SBAR; } while (0)

    // prologue: tile0 full + tile1 k0; oldest-first order for vmcnt math
    GU_STA(0, 0, 0); GU_STB(0, 0, 0);
    GU_STA(0, 1, 0); GU_STB(0, 1, 0);
    GU_STA(1, 0, 1); GU_STB(1, 0, 1);
    WVM8; SBAR;

#pragma unroll 1
    for (int u = 0; u < D_ / 128 - 1; ++u) {   // 7 iterations (NT=16)
        const int T1 = 2 * u + 1, TN = 2 * u + 2;
        GU_PH(0, 0, 0, 1, GU_STA(1, 1, T1), );
        GU_PH(0, 0, 1, 0, GU_STB(1, 1, T1), WVM8);
        GU_PH(0, 1, 0, 1, GU_STA(0, 0, TN), );
        GU_PH(0, 1, 1, 0, GU_STB(0, 0, TN), WVM8);
        GU_PH(1, 0, 0, 1, GU_STA(0, 1, TN), );
        GU_PH(1, 0, 1, 0, GU_STB(0, 1, TN), WVM8);
        GU_PH(1, 1, 0, 1, GU_STA(1, 0, TN + 1), );
        GU_PH(1, 1, 1, 0, GU_STB(1, 0, TN + 1), WVM8);
    }
    // epilogue iteration: tiles NT-2, NT-1; stage only buf1.k1 <- NT-1
    GU_PH(0, 0, 0, 1, GU_STA(1, 1, D_ / 64 - 1), );
    GU_PH(0, 0, 1, 0, GU_STB(1, 1, D_ / 64 - 1), WVM8);
    GU_PH(0, 1, 0, 1, , );
    GU_PH(0, 1, 1, 0, , WVM4);
    GU_PH(1, 0, 0, 1, , );
    GU_PH(1, 0, 1, 0, , WVM0);
    GU_PH(1, 1, 0, 1, , );
    GU_PH(1, 1, 1, 0, , );

    // C/D: col = lane&15, row = (lane>>4)*4 + reg
#pragma unroll
    for (int fi = 0; fi < 4; ++fi)
#pragma unroll
        for (int j = 0; j < 4; ++j)
#pragma unroll
            for (int r = 0; r < 4; ++r) {
                const int row = s0 + wr * 64 + fi * 16 + lq * 4 + r;
                const int col = f0 + wc * 64 + j * 16 + lm;
                H[((size_t)b * S_ + row) * F_ + col] =
                    f2b(gelu_exact(acc1[fi][j][r]) * acc2[fi][j][r]);
            }
#undef GU_STA
#undef GU_STB
#undef GU_RD
#undef GU_MM
#undef GU_PH
}

// ---------------- down: Y = H @ W2t^T ------------------
// Tile 256(s) x 256(d); wave grid 2x4 (wr=w>>2, wc=w&3); per-wave 128x64.
__global__ __launch_bounds__(512, 2)
void down_v3(const u16* __restrict__ H, const u16* __restrict__ W2t,
             const int* __restrict__ langs, float* __restrict__ Y)
{
    __shared__ u16 lds[65536];
    const int d0 = blockIdx.x * 256;
    const int s0 = blockIdx.y * 256;
    const int b  = blockIdx.z;
    const int e  = (langs[b] - 4) & 7;

    const int t    = threadIdx.x;
    const int lane = t & 63;
    const int w    = t >> 6;
    const int wr   = w >> 2, wc = w & 3;
    const int lm   = lane & 15, lq = lane >> 4;
    const int sr   = lane >> 2, sg = lane & 3;

    const u16* ha = H   + ((size_t)b * S_ + s0 + w * 32 + sr) * F_ + sg * 8;
    const u16* wa = W2t + ((size_t)e * D_ + d0 + w * 32 + sr) * F_ + sg * 8;
    const int aofs = w * 1024;

    f32x4 acc[8][4];
#pragma unroll
    for (int i = 0; i < 8; ++i)
#pragma unroll
        for (int j = 0; j < 4; ++j) acc[i][j] = (f32x4){0.f, 0.f, 0.f, 0.f};
    short8 a[4], bb[4];

#define DN_STA(bf, kh, kt) do { \
    gload_lds16(ha + (size_t)(kt) * 64 + (kh) * 32, \
                lds + (bf) * 32768 + (kh) * 8192 + aofs); \
    gload_lds16(ha + (size_t)16 * F_ + (size_t)(kt) * 64 + (kh) * 32, \
                lds + (bf) * 32768 + (kh) * 8192 + aofs + 512); } while (0)
#define DN_STB(bf, kh, kt) do { \
    gload_lds16(wa + (size_t)(kt) * 64 + (kh) * 32, \
                lds + (bf) * 32768 + 16384 + (kh) * 8192 + aofs); \
    gload_lds16(wa + (size_t)16 * F_ + (size_t)(kt) * 64 + (kh) * 32, \
                lds + (bf) * 32768 + 16384 + (kh) * 8192 + aofs + 512); } while (0)
#define DN_RD(bf, kh, qi, LOADB) do { \
    const u16* ab_ = lds + (bf) * 32768 + (kh) * 8192; \
    _Pragma("unroll") \
    for (int i = 0; i < 4; ++i) \
        a[i] = *(const short8*)(ab_ + (wr * 128 + (qi) * 64 + i * 16 + lm) * 32 + lq * 8); \
    if (LOADB) { \
        const u16* bb_ = ab_ + 16384; \
        _Pragma("unroll") \
        for (int j = 0; j < 4; ++j) \
            bb[j] = *(const short8*)(bb_ + (wc * 64 + j * 16 + lm) * 32 + lq * 8); \
    } } while (0)
#define DN_MM(qi) do { \
    __builtin_amdgcn_s_setprio(1); \
    _Pragma("unroll") \
    for (int i = 0; i < 4; ++i) \
    _Pragma("unroll") \
    for (int j = 0; j < 4; ++j) \
        acc[(qi)*4 + i][j] = __builtin_amdgcn_mfma_f32_16x16x32_bf16(a[i], bb[j], acc[(qi)*4 + i][j], 0, 0, 0); \
    __builtin_amdgcn_s_setprio(0); } while (0)
#define DN_PH(bf, kh, qi, LOADB, STG, WT) do { \
    DN_RD(bf, kh, qi, LOADB); STG; SBAR; DN_MM(qi); WT; WLG0; SBAR; } while (0)

    DN_STA(0, 0, 0); DN_STB(0, 0, 0);
    DN_STA(0, 1, 0); DN_STB(0, 1, 0);
    DN_STA(1, 0, 1); DN_STB(1, 0, 1);
    WVM8; SBAR;

#pragma unroll 1
    for (int u = 0; u < F_ / 128 - 1; ++u) {   // 31 iterations (NT=64)
        const int T1 = 2 * u + 1, TN = 2 * u + 2;
        DN_PH(0, 0, 0, 1, DN_STA(1, 1, T1), );
        DN_PH(0, 0, 1, 0, DN_STB(1, 1, T1), WVM8);
        DN_PH(0, 1, 0, 1, DN_STA(0, 0, TN), );
        DN_PH(0, 1, 1, 0, DN_STB(0, 0, TN), WVM8);
        DN_PH(1, 0, 0, 1, DN_STA(0, 1, TN), );
        DN_PH(1, 0, 1, 0, DN_STB(0, 1, TN), WVM8);
        DN_PH(1, 1, 0, 1, DN_STA(1, 0, TN + 1), );
        DN_PH(1, 1, 1, 0, DN_STB(1, 0, TN + 1), WVM8);
    }
    DN_PH(0, 0, 0, 1, DN_STA(1, 1, F_ / 64 - 1), );
    DN_PH(0, 0, 1, 0, DN_STB(1, 1, F_ / 64 - 1), WVM8);
    DN_PH(0, 1, 0, 1, , );
    DN_PH(0, 1, 1, 0, , WVM4);
    DN_PH(1, 0, 0, 1, , );
    DN_PH(1, 0, 1, 0, , WVM0);
    DN_PH(1, 1, 0, 1, , );
    DN_PH(1, 1, 1, 0, , );

#pragma unroll
    for (int fi = 0; fi < 8; ++fi)
#pragma unroll
        for (int j = 0; j < 4; ++j)
#pragma unroll
            for (int r = 0; r < 4; ++r) {
                const int row = s0 + wr * 128 + fi * 16 + lq * 4 + r;
                const int col = d0 + wc * 64 + j * 16 + lm;
                Y[((size_t)b * S_ + row) * D_ + col] = acc[fi][j][r];
            }
#undef DN_STA
#undef DN_STB
#undef DN_RD
#undef DN_MM
#undef DN_PH
}

// ===========================================================================
// Fallback path (R2 structure, f32 hard-coded) for small ws_size.
// ===========================================================================
__device__ __forceinline__ U16x8 load8f(const float* p, size_t off) {
    U16x8 r;
    const float4 v0 = *(const float4*)(p + off);
    const float4 v1 = *(const float4*)(p + off + 4);
    r.s[0] = f2b(v0.x); r.s[1] = f2b(v0.y); r.s[2] = f2b(v0.z); r.s[3] = f2b(v0.w);
    r.s[4] = f2b(v1.x); r.s[5] = f2b(v1.y); r.s[6] = f2b(v1.z); r.s[7] = f2b(v1.w);
    return r;
}

__global__ __launch_bounds__(256, 2)
void gateup_fb(const float* __restrict__ X, const float* __restrict__ W1,
               const float* __restrict__ W3, const int* __restrict__ langs,
               u16* __restrict__ H, int s_off, int schunk)
{
    __shared__ u16 sX [128 * 72];
    __shared__ u16 sW1[ 64 * 72];
    __shared__ u16 sW3[ 64 * 72];
    const int f0 = blockIdx.x * 64;
    const int sl = blockIdx.y * 128;
    const int b  = blockIdx.z;
    const int e  = (langs[b] - 4) & 7;
    const int t = threadIdx.x, lane = t & 63, w = t >> 6;
    const int wr = w >> 1, wc = w & 1, lm = lane & 15, lq = lane >> 4;
    const int wsel = t >> 7, idx = t & 127;
    const int wn = (idx & 7) * 8, wk = (idx >> 3) * 4;
    const float* Wsrc = wsel ? W3 : W1;
    u16* sWdst = wsel ? sW3 : sW1;

    f32x4 acc1[4][2], acc2[4][2];
#pragma unroll
    for (int i = 0; i < 4; ++i)
#pragma unroll
        for (int j = 0; j < 2; ++j) {
            acc1[i][j] = (f32x4){0.f,0.f,0.f,0.f};
            acc2[i][j] = (f32x4){0.f,0.f,0.f,0.f};
        }
    const size_t xbase = ((size_t)b * S_ + s_off + sl) * D_;
    const size_t wbase = (size_t)e * D_ * F_ + f0;
    for (int kt = 0; kt < D_ / 64; ++kt) {
        const int k0 = kt * 64;
        U16x8 xr[4], rr[4];
#pragma unroll
        for (int i = 0; i < 4; ++i) {
            const int ch = t + i * 256, row = ch >> 3, kk = (ch & 7) * 8;
            xr[i] = load8f(X, xbase + (size_t)row * D_ + k0 + kk);
        }
#pragma unroll
        for (int r = 0; r < 4; ++r)
            rr[r] = load8f(Wsrc, wbase + (size_t)(k0 + wk + r) * F_ + wn);
        __syncthreads();
#pragma unroll
        for (int i = 0; i < 4; ++i) {
            const int ch = t + i * 256, row = ch >> 3, kk = (ch & 7) * 8;
            *(uint4*)(sX + row * 72 + kk) = xr[i].v;
        }
#pragma unroll
        for (int j = 0; j < 8; ++j) {
            U16x4 o;
            o.s[0] = rr[0].s[j]; o.s[1] = rr[1].s[j];
            o.s[2] = rr[2].s[j]; o.s[3] = rr[3].s[j];
            *(uint2*)(sWdst + (wn + j) * 72 + wk) = o.v;
        }
        __syncthreads();
#pragma unroll
        for (int kk = 0; kk < 64; kk += 32) {
            short8 a[4], b1[2], b3[2];
#pragma unroll
            for (int i = 0; i < 4; ++i)
                a[i] = *(const short8*)(sX + (wr * 64 + i * 16 + lm) * 72 + kk + lq * 8);
#pragma unroll
            for (int j = 0; j < 2; ++j) {
                b1[j] = *(const short8*)(sW1 + (wc * 32 + j * 16 + lm) * 72 + kk + lq * 8);
                b3[j] = *(const short8*)(sW3 + (wc * 32 + j * 16 + lm) * 72 + kk + lq * 8);
            }
#pragma unroll
            for (int i = 0; i < 4; ++i)
#pragma unroll
                for (int j = 0; j < 2; ++j) {
                    acc1[i][j] = __builtin_amdgcn_mfma_f32_16x16x32_bf16(a[i], b1[j], acc1[i][j], 0, 0, 0);
                    acc2[i][j] = __builtin_amdgcn_mfma_f32_16x16x32_bf16(a[i], b3[j], acc2[i][j], 0, 0, 0);
                }
        }
    }
#pragma unroll
    for (int i = 0; i < 4; ++i)
#pragma unroll
        for (int j = 0; j < 2; ++j)
#pragma unroll
            for (int r = 0; r < 4; ++r) {
                const int row = wr * 64 + i * 16 + lq * 4 + r;
                const int col = wc * 32 + j * 16 + lm;
                H[((size_t)b * schunk + sl + row) * F_ + f0 + col] =
                    f2b(gelu_exact(acc1[i][j][r]) * acc2[i][j][r]);
            }
}

__global__ __launch_bounds__(256, 2)
void down_fb(const u16* __restrict__ Hm, const float* __restrict__ W2,
             const int* __restrict__ langs, float* __restrict__ Y,
             int s_off, int schunk)
{
    __shared__ u16 sH[128 * 72];
    __shared__ u16 sW[128 * 72];
    const int d0 = blockIdx.x * 128;
    const int sl = blockIdx.y * 128;
    const int b  = blockIdx.z;
    const int e  = (langs[b] - 4) & 7;
    const int t = threadIdx.x, lane = t & 63, w = t >> 6;
    const int wr = w >> 1, wc = w & 1, lm = lane & 15, lq = lane >> 4;
    const int wn = (t & 15) * 8, wk = (t >> 4) * 4;

    f32x4 acc[4][4];
#pragma unroll
    for (int i = 0; i < 4; ++i)
#pragma unroll
        for (int j = 0; j < 4; ++j) acc[i][j] = (f32x4){0.f,0.f,0.f,0.f};
    const size_t hbase = ((size_t)b * schunk + sl) * F_;
    const size_t wbase = (size_t)e * F_ * D_ + d0;
    for (int kt = 0; kt < F_ / 64; ++kt) {
        const int k0 = kt * 64;
        U16x8 hr[4], rr[4];
#pragma unroll
        for (int i = 0; i < 4; ++i) {
            const int ch = t + i * 256, row = ch >> 3, kk = (ch & 7) * 8;
            hr[i].v = *(const uint4*)(Hm + hbase + (size_t)row * F_ + k0 + kk);
        }
#pragma unroll
        for (int r = 0; r < 4; ++r)
            rr[r] = load8f(W2, wbase + (size_t)(k0 + wk + r) * D_ + wn);
        __syncthreads();
#pragma unroll
        for (int i = 0; i < 4; ++i) {
            const int ch = t + i * 256, row = ch >> 3, kk = (ch & 7) * 8;
            *(uint4*)(sH + row * 72 + kk) = hr[i].v;
        }
#pragma unroll
        for (int j = 0; j < 8; ++j) {
            U16x4 o;
            o.s[0] = rr[0].s[j]; o.s[1] = rr[1].s[j];
            o.s[2] = rr[2].s[j]; o.s[3] = rr[3].s[j];
            *(uint2*)(sW + (wn + j) * 72 + wk) = o.v;
        }
        __syncthreads();
#pragma unroll
        for (int kk = 0; kk < 64; kk += 32) {
            short8 a[4], bb[4];
#pragma unroll
            for (int i = 0; i < 4; ++i)
                a[i] = *(const short8*)(sH + (wr * 64 + i * 16 + lm) * 72 + kk + lq * 8);
#pragma unroll
            for (int j = 0; j < 4; ++j)
                bb[j] = *(const short8*)(sW + (wc * 64 + j * 16 + lm) * 72 + kk + lq * 8);
#pragma unroll
            for (int i = 0; i < 4; ++i)
#pragma unroll
                for (int j = 0; j < 4; ++j)
                    acc[i][j] = __builtin_amdgcn_mfma_f32_16x16x32_bf16(a[i], bb[j], acc[i][j], 0, 0, 0);
        }
    }
#pragma unroll
    for (int i = 0; i < 4; ++i)
#pragma unroll
        for (int j = 0; j < 4; ++j)
#pragma unroll
            for (int r = 0; r < 4; ++r) {
                const int row = wr * 64 + i * 16 + lq * 4 + r;
                const int col = wc * 64 + j * 16 + lm;
                Y[((size_t)b * S_ + s_off + sl + row) * D_ + d0 + col] = acc[i][j][r];
            }
}

extern "C" void kernel_launch(void* const* d_in, const int* in_sizes, int n_in,
                              void* d_out, int out_size, void* d_ws, size_t ws_size,
                              hipStream_t stream) {
    // dict order: hidden_states, w1, w2, w3, langs (w2 BEFORE w3)
    const float* X  = (const float*)d_in[0];
    const float* W1 = (const float*)d_in[1];
    const float* W2 = (const float*)d_in[2];
    const float* W3 = (const float*)d_in[3];
    const int* langs = (const int*)d_in[4];
    float* Y = (float*)d_out;

    const size_t szXb = (size_t)B_ * S_ * D_ * 2;   //  32 MiB
    const size_t szW  = (size_t)E_ * F_ * D_ * 2;   //  64 MiB
    const size_t szH  = (size_t)B_ * S_ * F_ * 2;   // 128 MiB
    const size_t need = szXb + 2 * szW + szH;       // 288 MiB

    if (ws_size >= need) {
        u16* Xb  = (u16*)d_ws;
        u16* W1t = (u16*)((char*)d_ws + szXb);
        u16* W3t = (u16*)((char*)d_ws + szXb + szW);
        u16* W2t = W1t;   // reused after gateup (stream-ordered)
        u16* Hb  = (u16*)((char*)d_ws + szXb + 2 * szW);

        convert_x<<<(B_ * S_ * D_) / (256 * 8), 256, 0, stream>>>(X, Xb);
        dim3 gt1(F_ / 64, D_ / 64, E_);
        transpose_w<<<gt1, 256, 0, stream>>>(W1, W1t, D_, F_);
        transpose_w<<<gt1, 256, 0, stream>>>(W3, W3t, D_, F_);
        dim3 g1(F_ / 128, S_ / 256, B_);          // 32 x 8 x 8
        gateup_v3<<<g1, 512, 0, stream>>>(Xb, W1t, W3t, langs, Hb);
        dim3 gt2(D_ / 64, F_ / 64, E_);
        transpose_w<<<gt2, 256, 0, stream>>>(W2, W2t, F_, D_);
        dim3 g2(D_ / 256, S_ / 256, B_);          // 4 x 8 x 8
        down_v3<<<g2, 512, 0, stream>>>(Hb, W2t, langs, Y);
    } else {
        u16* H = (u16*)d_ws;
        const size_t slab = (size_t)B_ * F_ * 2 * 128;
        int nslabs = (int)(ws_size / slab);
        if (nslabs < 1) nslabs = 1;
        if (nslabs > S_ / 128) nslabs = S_ / 128;
        const int SCH = nslabs * 128;
        for (int s0 = 0; s0 < S_; s0 += SCH) {
            const int rows = (S_ - s0 < SCH) ? (S_ - s0) : SCH;
            dim3 g1(F_ / 64, rows / 128, B_);
            gateup_fb<<<g1, 256, 0, stream>>>(X, W1, W3, langs, H, s0, SCH);
            dim3 g2(D_ / 128, rows / 128, B_);
            down_fb<<<g2, 256, 0, stream>>>(H, W2, langs, Y, s0, SCH);
        }
    }
}